// Round 1
// 122.320 us; speedup vs baseline: 1.0262x; 1.0262x over previous
//
#include <hip/hip_runtime.h>

// HausdorffLoss (average): B=8, N=M=4096, C=128, fp32 in/out.
// R9: barrier-free main loop. R8's per-iteration __syncthreads drained
// vmcnt(0) -> exposed the B-tile staging latency AND the 2 global atomicMin
// round-trips on every iteration for every wave (MfmaUtil 25%, 40% idle).
// Changes:
//   - B fragments loaded global->register (double-buffered, prefetch 1).
//     Same addresses as the old LDS reads (prep swizzle cancels: col&15==lm),
//     so prep_kernel is unchanged. No LDS staging, no loop barriers; the
//     compiler's per-register vmcnt(N) gives a counted-vmcnt pipeline.
//   - A fragments also direct global->reg (one-time prologue).
//   - NO global atomics: col mins accumulate in owner-wave LDS slots
//     (exclusive (row-half,col) ownership -> plain rmw); row mins in regs.
//     One __syncthreads at the end, plain coalesced stores to partial
//     buffers rowpart[4][B][N], colpart[32][B][M]; reduce kernel mins them.
//   - Epilogue col-min restructured as trees (no 32-deep fmin chain).
#define B_ 8
#define N_ 4096
#define M_ 4096
#define C_ 128
#define BN_ (B_ * N_)
#define BM_ (B_ * M_)

typedef __attribute__((ext_vector_type(8))) short bf16x8;    // MFMA A/B frag
typedef __attribute__((ext_vector_type(4))) float floatx4;   // MFMA C/D frag
typedef __attribute__((ext_vector_type(8))) unsigned short ushort8;

// fp32 -> bf16 round-to-nearest-even
__device__ __forceinline__ unsigned short f2bf(float x) {
    unsigned int u = __float_as_uint(x);
    u += 0x7FFFu + ((u >> 16) & 1u);
    return (unsigned short)(u >> 16);
}

// ---------------------------------------------------------------------------
// Prep: bf16 convert (swizzled: ws[row][g ^ (row&15)] = src[row][g]),
// norms[row] = ||row||^2 (fp32), out zero-init.
// Wave handles 4 rows: lane = (row_in_4 : 2, k-group : 4).
// Grid = (BN_+BM_)/16 = 4096 blocks x 256 threads.
// ---------------------------------------------------------------------------
__global__ __launch_bounds__(256) void prep_kernel(
    const float* __restrict__ S1, const float* __restrict__ S2,
    float* __restrict__ norms, unsigned short* __restrict__ bfA,
    unsigned short* __restrict__ bfB, float* __restrict__ out) {
    const int lane = threadIdx.x & 63;
    const int w    = threadIdx.x >> 6;
    const int gw   = blockIdx.x * 4 + w;
    const int r4   = lane >> 4;
    const int g4   = lane & 15;
    const int row  = gw * 4 + r4;          // 0 .. BN_+BM_-1

    const float* src = (row < BN_) ? S1 + (size_t)row * C_
                                   : S2 + (size_t)(row - BN_) * C_;
    float4 v0 = ((const float4*)src)[g4 * 2];
    float4 v1 = ((const float4*)src)[g4 * 2 + 1];

    float s = v0.x*v0.x + v0.y*v0.y + v0.z*v0.z + v0.w*v0.w
            + v1.x*v1.x + v1.y*v1.y + v1.z*v1.z + v1.w*v1.w;
    s += __shfl_xor(s, 1, 64);
    s += __shfl_xor(s, 2, 64);
    s += __shfl_xor(s, 4, 64);
    s += __shfl_xor(s, 8, 64);

    ushort8 o;
    o[0] = f2bf(v0.x); o[1] = f2bf(v0.y); o[2] = f2bf(v0.z); o[3] = f2bf(v0.w);
    o[4] = f2bf(v1.x); o[5] = f2bf(v1.y); o[6] = f2bf(v1.z); o[7] = f2bf(v1.w);

    unsigned short* dst = (row < BN_) ? bfA + (size_t)row * C_
                                      : bfB + (size_t)(row - BN_) * C_;
    *(ushort8*)&dst[(g4 ^ (row & 15)) * 8] = o;

    if (g4 == 0) norms[row] = s;
    if (blockIdx.x == 0 && threadIdx.x < B_) out[threadIdx.x] = 0.f;
}

// ---------------------------------------------------------------------------
// Main: grid (N/128, M/1024, B). 4 waves; wave tile = 64 rows x 32 cols.
// No LDS staging; no barriers in the K-loop. LDS only holds min accumulators.
// ---------------------------------------------------------------------------

// B-fragment load, global -> registers. Swizzle XOR cancels prep's store
// swizzle because (qc + 16*j + lm) & 15 == lm.
#define LOADB(dst_, it_)                                                      \
  do {                                                                        \
    const unsigned short* Bt_ = Bws + (size_t)(it_) * (64 * C_);              \
    _Pragma("unroll")                                                         \
    for (int j_ = 0; j_ < 2; ++j_)                                            \
      _Pragma("unroll")                                                       \
      for (int c_ = 0; c_ < 4; ++c_)                                          \
        dst_[j_][c_] = *(const bf16x8*)                                       \
            &Bt_[(qc + 16 * j_ + lm) * 128 + (((c_ * 4 + quad) ^ lm) * 8)];   \
  } while (0)

#define BODY(cur_, nxt_, it_)                                                 \
  do {                                                                        \
    const int itv_ = (it_);                                                   \
    if (itv_ + 1 < 16) LOADB(nxt_, itv_ + 1);                                 \
    const float sb0_ = bsq[itv_ * 64 + qc + lm];                              \
    const float sb1_ = bsq[itv_ * 64 + qc + 16 + lm];                         \
    floatx4 acc_[4][2] = {};                                                  \
    _Pragma("unroll")                                                         \
    for (int c_ = 0; c_ < 4; ++c_)                                            \
      _Pragma("unroll")                                                       \
      for (int i_ = 0; i_ < 4; ++i_)                                          \
        _Pragma("unroll")                                                     \
        for (int j_ = 0; j_ < 2; ++j_)                                        \
          acc_[i_][j_] = __builtin_amdgcn_mfma_f32_16x16x32_bf16(             \
              af[i_][c_], cur_[j_][c_], acc_[i_][j_], 0, 0, 0);               \
    float cvp0a_ = 1e30f, cvp0b_ = 1e30f, cvp1a_ = 1e30f, cvp1b_ = 1e30f;     \
    _Pragma("unroll")                                                         \
    for (int i_ = 0; i_ < 4; ++i_) {                                          \
      float d0_[4], d1_[4];                                                   \
      _Pragma("unroll")                                                       \
      for (int r_ = 0; r_ < 4; ++r_) {                                        \
        d0_[r_] = fmaf(-2.0f, acc_[i_][0][r_], sa[4 * i_ + r_] + sb0_);       \
        d1_[r_] = fmaf(-2.0f, acc_[i_][1][r_], sa[4 * i_ + r_] + sb1_);       \
        rv[4 * i_ + r_] = fminf(rv[4 * i_ + r_], fminf(d0_[r_], d1_[r_]));    \
      }                                                                       \
      float m0_ = fminf(fminf(d0_[0], d0_[1]), fminf(d0_[2], d0_[3]));        \
      float m1_ = fminf(fminf(d1_[0], d1_[1]), fminf(d1_[2], d1_[3]));        \
      if (i_ & 1) { cvp0b_ = fminf(cvp0b_, m0_); cvp1b_ = fminf(cvp1b_, m1_); } \
      else        { cvp0a_ = fminf(cvp0a_, m0_); cvp1a_ = fminf(cvp1a_, m1_); } \
    }                                                                         \
    float cv0_ = fminf(cvp0a_, cvp0b_), cv1_ = fminf(cvp1a_, cvp1b_);         \
    cv0_ = fminf(cv0_, __shfl_xor(cv0_, 16, 64));                             \
    cv0_ = fminf(cv0_, __shfl_xor(cv0_, 32, 64));                             \
    cv1_ = fminf(cv1_, __shfl_xor(cv1_, 16, 64));                             \
    cv1_ = fminf(cv1_, __shfl_xor(cv1_, 32, 64));                             \
    if (quad == 0) {                                                          \
      const int c0_ = itv_ * 64 + qc + lm;                                    \
      colmin_lds[rh][c0_]      = fminf(colmin_lds[rh][c0_], cv0_);            \
      colmin_lds[rh][c0_ + 16] = fminf(colmin_lds[rh][c0_ + 16], cv1_);       \
    }                                                                         \
  } while (0)

__global__ __launch_bounds__(256, 2) void hausdorff_mfma(
    const unsigned short* __restrict__ Abf, const unsigned short* __restrict__ Bbf,
    const float* __restrict__ asq_g, const float* __restrict__ bsq_g,
    float* __restrict__ rowpart, float* __restrict__ colpart) {

    __shared__ float colmin_lds[2][1024];   // [row-half][panel col]
    __shared__ float rowmin_lds[2][128];    // [col-half][block row]

    const int b     = blockIdx.z;
    const int row0  = blockIdx.x * 128;
    const int panel = blockIdx.y;                   // cols panel*1024 ..
    const int tid   = threadIdx.x;
    const int lane  = tid & 63;
    const int w     = tid >> 6;
    const int lm    = lane & 15;
    const int quad  = lane >> 4;
    const int wrow  = (w >> 1) * 64;                // wave's row half
    const int qc    = (w & 1) * 32;                 // wave's col half (of 64)
    const int rh    = w >> 1;                       // colmin slot owner
    const int ch    = w & 1;                        // rowmin slot owner

    const unsigned short* Aws = Abf + ((size_t)b * N_ + row0 + wrow) * C_;
    const unsigned short* Bws = Bbf + ((size_t)b * M_ + (size_t)panel * 1024) * C_;
    const float* bsq = bsq_g + (size_t)b * M_ + panel * 1024;

    // owner-wave init of colmin accumulators (exclusive access -> no barrier)
    if (quad == 0) {
        #pragma unroll
        for (int it = 0; it < 16; ++it) {
            colmin_lds[rh][it * 64 + qc + lm]      = 1e30f;
            colmin_lds[rh][it * 64 + qc + 16 + lm] = 1e30f;
        }
    }

    // A fragments: direct global->reg, one time (swizzle cancels: row&15==lm)
    bf16x8 af[4][4];
    #pragma unroll
    for (int i = 0; i < 4; ++i)
        #pragma unroll
        for (int c = 0; c < 4; ++c)
            af[i][c] = *(const bf16x8*)
                &Aws[(16 * i + lm) * 128 + (((c * 4 + quad) ^ lm) * 8)];

    // row norms for this lane's 16 rows: wrow + 16i + 4*quad + reg
    float sa[16];
    #pragma unroll
    for (int i = 0; i < 4; ++i) {
        float4 t = *(const float4*)&asq_g[(size_t)b * N_ + row0 + wrow + 16 * i + 4 * quad];
        sa[4*i+0] = t.x; sa[4*i+1] = t.y; sa[4*i+2] = t.z; sa[4*i+3] = t.w;
    }

    float rv[16];
    #pragma unroll
    for (int v = 0; v < 16; ++v) rv[v] = 1e30f;

    // barrier-free K-loop, B frags double-buffered in registers
    bf16x8 bfa[2][4], bfb[2][4];
    LOADB(bfa, 0);
    for (int it = 0; it < 16; it += 2) {
        BODY(bfa, bfb, it);
        BODY(bfb, bfa, it + 1);
    }

    // row mins: butterfly across the 16 lane-cols, then stash per col-half
    #pragma unroll
    for (int s = 1; s < 16; s <<= 1)
        #pragma unroll
        for (int v = 0; v < 16; ++v)
            rv[v] = fminf(rv[v], __shfl_xor(rv[v], s, 64));
    if (lm == 0) {
        #pragma unroll
        for (int v = 0; v < 16; ++v)
            rowmin_lds[ch][wrow + 16 * (v >> 2) + 4 * quad + (v & 3)] = rv[v];
    }

    __syncthreads();   // the only barrier

    // flush col partials: combine row halves, plain coalesced stores
    #pragma unroll
    for (int k = 0; k < 4; ++k) {
        const int c = tid + 256 * k;
        colpart[((size_t)blockIdx.x * B_ + b) * M_ + (size_t)panel * 1024 + c] =
            fminf(colmin_lds[0][c], colmin_lds[1][c]);
    }
    // flush row partials: combine col halves
    if (tid < 128)
        rowpart[((size_t)panel * B_ + b) * N_ + row0 + tid] =
            fminf(rowmin_lds[0][tid], rowmin_lds[1][tid]);
}

// ---------------------------------------------------------------------------
// Reduce: 64 blocks (8 per batch). rows: min over 4 panel partials;
// cols: min over 32 row-block partials; then sqrt-mean -> atomicAdd(out[b]).
// ---------------------------------------------------------------------------
__global__ __launch_bounds__(256) void hausdorff_reduce(
    const float* __restrict__ rowpart, const float* __restrict__ colpart,
    float* __restrict__ out) {
    __shared__ float ws4[4];
    const int b    = blockIdx.x >> 3;
    const int part = blockIdx.x & 7;
    const int base = part * 512;
    float s = 0.f;
    for (int i = base + (int)threadIdx.x; i < base + 512; i += 256) {
        float ra = fminf(rowpart[((size_t)0 * B_ + b) * N_ + i],
                         rowpart[((size_t)1 * B_ + b) * N_ + i]);
        float rb = fminf(rowpart[((size_t)2 * B_ + b) * N_ + i],
                         rowpart[((size_t)3 * B_ + b) * N_ + i]);
        float rm = fminf(ra, rb);
        float ca = 1e30f, cb = 1e30f;
        #pragma unroll
        for (int x = 0; x < 32; x += 2) {
            ca = fminf(ca, colpart[((size_t)x * B_ + b) * M_ + i]);
            cb = fminf(cb, colpart[((size_t)(x + 1) * B_ + b) * M_ + i]);
        }
        float cm = fminf(ca, cb);
        s += sqrtf(fmaxf(rm, 0.f)) * (1.f / N_)
           + sqrtf(fmaxf(cm, 0.f)) * (1.f / M_);
    }
    #pragma unroll
    for (int off = 32; off > 0; off >>= 1) s += __shfl_down(s, off, 64);
    if ((threadIdx.x & 63) == 0) ws4[threadIdx.x >> 6] = s;
    __syncthreads();
    if (threadIdx.x == 0)
        atomicAdd(&out[b], ws4[0] + ws4[1] + ws4[2] + ws4[3]);
}

extern "C" void kernel_launch(void* const* d_in, const int* in_sizes, int n_in,
                              void* d_out, int out_size, void* d_ws, size_t ws_size,
                              hipStream_t stream) {
    const float* s1 = (const float*)d_in[0];
    const float* s2 = (const float*)d_in[1];
    float* out = (float*)d_out;

    // ws: norms(BN+BM f32) | bfA | bfB | rowpart[4][B][N] | colpart[32][B][M]
    float* norms         = (float*)d_ws;
    unsigned short* bfA  = (unsigned short*)(norms + BN_ + BM_);
    unsigned short* bfB  = bfA + (size_t)BN_ * C_;
    float* rowpart       = (float*)(bfB + (size_t)BM_ * C_);
    float* colpart       = rowpart + (size_t)4 * B_ * N_;

    prep_kernel<<<(BN_ + BM_) / 16, 256, 0, stream>>>(
        s1, s2, norms, bfA, bfB, out);

    dim3 grid(N_ / 128, M_ / 1024, B_);
    hausdorff_mfma<<<grid, 256, 0, stream>>>(
        bfA, bfB, norms, norms + BN_, rowpart, colpart);

    hausdorff_reduce<<<B_ * 8, 256, 0, stream>>>(rowpart, colpart, out);
}

// Round 2
// 121.747 us; speedup vs baseline: 1.0311x; 1.0047x over previous
//
#include <hip/hip_runtime.h>

// HausdorffLoss (average): B=8, N=M=4096, C=128, fp32 in/out.
// R10: recombine R8's coalesced gl2lds staging (R9's direct global->reg B
// loads were uncoalesced: 64 scattered 16B chunks per instr -> L2 request
// storm, 56us) with R9's atomic-free epilogue (R8's per-iter stall was the
// vmcnt(0) drain of the just-issued global atomicMins at each barrier).
// New: "e-trick" -- prep stores -0.5*||x||^2; MFMA acc is initialized to
// ha+hb so acc = inner - (sa+sb)/2 = -d^2/2. min d^2 == -2*max e, so the
// epilogue is pure max-trees (v_max3): deletes 32 fma + 32 zero-init per
// BODY (~50% of epilogue VALU). Clamp to 0 deferred to the reduce kernel.
// One __syncthreads per iteration; its vmcnt drain only waits on gl2lds
// issued a full iteration earlier (complete -> free).
#define B_ 8
#define N_ 4096
#define M_ 4096
#define C_ 128
#define BN_ (B_ * N_)
#define BM_ (B_ * M_)

typedef __attribute__((ext_vector_type(8))) short bf16x8;    // MFMA A/B frag
typedef __attribute__((ext_vector_type(4))) float floatx4;   // MFMA C/D frag
typedef __attribute__((ext_vector_type(8))) unsigned short ushort8;

// fp32 -> bf16 round-to-nearest-even
__device__ __forceinline__ unsigned short f2bf(float x) {
    unsigned int u = __float_as_uint(x);
    u += 0x7FFFu + ((u >> 16) & 1u);
    return (unsigned short)(u >> 16);
}

// async global->LDS, 16 B per lane; LDS dest = wave-uniform base + lane*16
__device__ __forceinline__ void gl2lds16(const void* g, void* l) {
    __builtin_amdgcn_global_load_lds(
        (const __attribute__((address_space(1))) void*)g,
        (__attribute__((address_space(3))) void*)l, 16, 0, 0);
}

// ---------------------------------------------------------------------------
// Prep: bf16 convert (swizzled: ws[row][g ^ (row&15)] = src[row][g]),
// norms[row] = -0.5 * ||row||^2 (fp32, pre-scaled for the e-trick), out zero.
// Wave handles 4 rows: lane = (row_in_4 : 2, k-group : 4).
// Grid = (BN_+BM_)/16 = 4096 blocks x 256 threads.
// ---------------------------------------------------------------------------
__global__ __launch_bounds__(256) void prep_kernel(
    const float* __restrict__ S1, const float* __restrict__ S2,
    float* __restrict__ norms, unsigned short* __restrict__ bfA,
    unsigned short* __restrict__ bfB, float* __restrict__ out) {
    const int lane = threadIdx.x & 63;
    const int w    = threadIdx.x >> 6;
    const int gw   = blockIdx.x * 4 + w;
    const int r4   = lane >> 4;
    const int g4   = lane & 15;
    const int row  = gw * 4 + r4;          // 0 .. BN_+BM_-1

    const float* src = (row < BN_) ? S1 + (size_t)row * C_
                                   : S2 + (size_t)(row - BN_) * C_;
    float4 v0 = ((const float4*)src)[g4 * 2];
    float4 v1 = ((const float4*)src)[g4 * 2 + 1];

    float s = v0.x*v0.x + v0.y*v0.y + v0.z*v0.z + v0.w*v0.w
            + v1.x*v1.x + v1.y*v1.y + v1.z*v1.z + v1.w*v1.w;
    s += __shfl_xor(s, 1, 64);
    s += __shfl_xor(s, 2, 64);
    s += __shfl_xor(s, 4, 64);
    s += __shfl_xor(s, 8, 64);

    ushort8 o;
    o[0] = f2bf(v0.x); o[1] = f2bf(v0.y); o[2] = f2bf(v0.z); o[3] = f2bf(v0.w);
    o[4] = f2bf(v1.x); o[5] = f2bf(v1.y); o[6] = f2bf(v1.z); o[7] = f2bf(v1.w);

    unsigned short* dst = (row < BN_) ? bfA + (size_t)row * C_
                                      : bfB + (size_t)(row - BN_) * C_;
    *(ushort8*)&dst[(g4 ^ (row & 15)) * 8] = o;

    if (g4 == 0) norms[row] = -0.5f * s;
    if (blockIdx.x == 0 && threadIdx.x < B_) out[threadIdx.x] = 0.f;
}

// ---------------------------------------------------------------------------
// Main: grid (N/128, M/1024, B). 4 waves; wave tile = 64 rows x 32 cols.
// LDS: two 16 KB buffers. Pre-loop they hold the A tile (rows 0-63 / 64-127);
// in the loop they double-buffer 64-col B tiles. Plus max-accumulator arrays.
// ---------------------------------------------------------------------------
__global__ __launch_bounds__(256, 2) void hausdorff_mfma(
    const unsigned short* __restrict__ Abf, const unsigned short* __restrict__ Bbf,
    const float* __restrict__ ahalf_g, const float* __restrict__ bhalf_g,
    float* __restrict__ rowpart, float* __restrict__ colpart) {

    __shared__ unsigned short B_lds[2][64 * 128];   // 2 x 16 KB
    __shared__ float colmax_lds[2][1024];           // [row-half][panel col]
    __shared__ float rowmax_lds[2][128];            // [col-half][block row]

    const int b     = blockIdx.z;
    const int row0  = blockIdx.x * 128;
    const int panel = blockIdx.y;                   // cols panel*1024 ..
    const int tid   = threadIdx.x;
    const int lane  = tid & 63;
    const int w     = tid >> 6;
    const int lm    = lane & 15;
    const int quad  = lane >> 4;
    const int wrow  = (w >> 1) * 64;                // wave's row half
    const int qc    = (w & 1) * 32;                 // wave's col half (of 64)
    const int rh    = w >> 1;                       // colmax slot owner
    const int ch    = w & 1;                        // rowmax slot owner

    const unsigned short* Aws = Abf + ((size_t)b * N_ + row0) * C_;
    const unsigned short* Bws = Bbf + ((size_t)b * M_ + (size_t)panel * 1024) * C_;
    const float* bhalf = bhalf_g + (size_t)b * M_ + panel * 1024;

    // owner-wave init of colmax accumulators (exclusive access, no barrier)
    if (quad == 0) {
        #pragma unroll
        for (int it = 0; it < 16; ++it) {
            colmax_lds[rh][it * 64 + qc + lm]      = -1e30f;
            colmax_lds[rh][it * 64 + qc + 16 + lm] = -1e30f;
        }
    }

    // ---- stage A through both buffers: rows 0-63 -> buf0, 64-127 -> buf1
    #pragma unroll
    for (int k = 0; k < 4; ++k) {
        const int off = w * 2048 + k * 512;         // ushorts
        gl2lds16(Aws + off + lane * 8,        &B_lds[0][off]);
        gl2lds16(Aws + 8192 + off + lane * 8, &B_lds[1][off]);
    }

    // -0.5*||a||^2 for this lane's 16 rows: wrow + 16i + 4*quad + reg
    float ha[16];
    #pragma unroll
    for (int i = 0; i < 4; ++i) {
        float4 t = *(const float4*)&ahalf_g[(size_t)b * N_ + row0 + wrow + 16 * i + 4 * quad];
        ha[4*i+0] = t.x; ha[4*i+1] = t.y; ha[4*i+2] = t.z; ha[4*i+3] = t.w;
    }

    float rv[16];                                   // running e-max per row
    #pragma unroll
    for (int v = 0; v < 16; ++v) rv[v] = -1e30f;

    __syncthreads();   // A staged

    // A fragments once; waves 0,1 from buf0 (rows 0-63), waves 2,3 from buf1
    bf16x8 af[4][4];
    {
        const unsigned short* Abuf = &B_lds[w >> 1][0];
        #pragma unroll
        for (int i = 0; i < 4; ++i)
            #pragma unroll
            for (int c = 0; c < 4; ++c)
                af[i][c] = *(const bf16x8*)
                    &Abuf[(16 * i + lm) * 128 + (((c * 4 + quad) ^ lm) * 8)];
    }

    __syncthreads();   // all af reads done -> buffers reusable

    // stage B tile 0 into buf0
    #pragma unroll
    for (int k = 0; k < 4; ++k) {
        const int off = w * 2048 + k * 512;
        gl2lds16(Bws + off + lane * 8, &B_lds[0][off]);
    }

    for (int it = 0; it < 16; ++it) {
        const int cur = it & 1;
        __syncthreads();   // tile `it` staged (its loads a full iter old)

        if (it < 15) {     // stage next tile into the other buffer
            const unsigned short* Bt = Bws + (size_t)(it + 1) * 64 * C_;
            #pragma unroll
            for (int k = 0; k < 4; ++k) {
                const int off = w * 2048 + k * 512;
                gl2lds16(Bt + off + lane * 8, &B_lds[cur ^ 1][off]);
            }
        }
        const float hb0 = bhalf[it * 64 + qc + lm];
        const float hb1 = bhalf[it * 64 + qc + 16 + lm];

        bf16x8 bf[2][4];
        #pragma unroll
        for (int j = 0; j < 2; ++j)
            #pragma unroll
            for (int c = 0; c < 4; ++c)
                bf[j][c] = *(const bf16x8*)
                    &B_lds[cur][(qc + 16 * j + lm) * 128 + (((c * 4 + quad) ^ lm) * 8)];

        // acc init = ha + hb  ->  acc accumulates to  inner - (sa+sb)/2
        floatx4 acc[4][2];
        #pragma unroll
        for (int i = 0; i < 4; ++i)
            #pragma unroll
            for (int r = 0; r < 4; ++r) {
                acc[i][0][r] = ha[4 * i + r] + hb0;
                acc[i][1][r] = ha[4 * i + r] + hb1;
            }
        #pragma unroll
        for (int c = 0; c < 4; ++c)
            #pragma unroll
            for (int i = 0; i < 4; ++i)
                #pragma unroll
                for (int j = 0; j < 2; ++j)
                    acc[i][j] = __builtin_amdgcn_mfma_f32_16x16x32_bf16(
                        af[i][c], bf[j][c], acc[i][j], 0, 0, 0);

        // pure max epilogue (min d^2 == -2 * max e)
        float cv0a = -1e30f, cv0b = -1e30f, cv1a = -1e30f, cv1b = -1e30f;
        #pragma unroll
        for (int i = 0; i < 4; ++i) {
            #pragma unroll
            for (int r = 0; r < 4; ++r)
                rv[4 * i + r] = fmaxf(rv[4 * i + r],
                                      fmaxf(acc[i][0][r], acc[i][1][r]));  // v_max3
            float m0 = fmaxf(fmaxf(acc[i][0][0], acc[i][0][1]),
                             fmaxf(acc[i][0][2], acc[i][0][3]));
            float m1 = fmaxf(fmaxf(acc[i][1][0], acc[i][1][1]),
                             fmaxf(acc[i][1][2], acc[i][1][3]));
            if (i & 1) { cv0b = fmaxf(cv0b, m0); cv1b = fmaxf(cv1b, m1); }
            else       { cv0a = fmaxf(cv0a, m0); cv1a = fmaxf(cv1a, m1); }
        }
        float cv0 = fmaxf(cv0a, cv0b), cv1 = fmaxf(cv1a, cv1b);
        cv0 = fmaxf(cv0, __shfl_xor(cv0, 16, 64));
        cv0 = fmaxf(cv0, __shfl_xor(cv0, 32, 64));
        cv1 = fmaxf(cv1, __shfl_xor(cv1, 16, 64));
        cv1 = fmaxf(cv1, __shfl_xor(cv1, 32, 64));
        if (quad == 0) {
            const int c0 = it * 64 + qc + lm;
            colmax_lds[rh][c0]      = fmaxf(colmax_lds[rh][c0], cv0);
            colmax_lds[rh][c0 + 16] = fmaxf(colmax_lds[rh][c0 + 16], cv1);
        }
    }

    // row maxes: butterfly across the 16 lane-cols, then stash per col-half
    #pragma unroll
    for (int s = 1; s < 16; s <<= 1)
        #pragma unroll
        for (int v = 0; v < 16; ++v)
            rv[v] = fmaxf(rv[v], __shfl_xor(rv[v], s, 64));
    if (lm == 0) {
        #pragma unroll
        for (int v = 0; v < 16; ++v)
            rowmax_lds[ch][wrow + 16 * (v >> 2) + 4 * quad + (v & 3)] = rv[v];
    }

    __syncthreads();

    // flush col partials: combine row halves, plain coalesced stores
    #pragma unroll
    for (int k = 0; k < 4; ++k) {
        const int c = tid + 256 * k;
        colpart[((size_t)blockIdx.x * B_ + b) * M_ + (size_t)panel * 1024 + c] =
            fmaxf(colmax_lds[0][c], colmax_lds[1][c]);
    }
    // flush row partials: combine col halves
    if (tid < 128)
        rowpart[((size_t)panel * B_ + b) * N_ + row0 + tid] =
            fmaxf(rowmax_lds[0][tid], rowmax_lds[1][tid]);
}

// ---------------------------------------------------------------------------
// Reduce: 64 blocks (8 per batch). rows: max-e over 4 panel partials;
// cols: max-e over 32 row-block partials; d^2 = max(-2e, 0); sqrt-mean.
// ---------------------------------------------------------------------------
__global__ __launch_bounds__(256) void hausdorff_reduce(
    const float* __restrict__ rowpart, const float* __restrict__ colpart,
    float* __restrict__ out) {
    __shared__ float ws4[4];
    const int b    = blockIdx.x >> 3;
    const int part = blockIdx.x & 7;
    const int base = part * 512;
    float s = 0.f;
    for (int i = base + (int)threadIdx.x; i < base + 512; i += 256) {
        float ra = fmaxf(rowpart[((size_t)0 * B_ + b) * N_ + i],
                         rowpart[((size_t)1 * B_ + b) * N_ + i]);
        float rb = fmaxf(rowpart[((size_t)2 * B_ + b) * N_ + i],
                         rowpart[((size_t)3 * B_ + b) * N_ + i]);
        float rm = fmaxf(ra, rb);
        float ca = -1e30f, cb = -1e30f;
        #pragma unroll
        for (int x = 0; x < 32; x += 2) {
            ca = fmaxf(ca, colpart[((size_t)x * B_ + b) * M_ + i]);
            cb = fmaxf(cb, colpart[((size_t)(x + 1) * B_ + b) * M_ + i]);
        }
        float cm = fmaxf(ca, cb);
        s += sqrtf(fmaxf(-2.f * rm, 0.f)) * (1.f / N_)
           + sqrtf(fmaxf(-2.f * cm, 0.f)) * (1.f / M_);
    }
    #pragma unroll
    for (int off = 32; off > 0; off >>= 1) s += __shfl_down(s, off, 64);
    if ((threadIdx.x & 63) == 0) ws4[threadIdx.x >> 6] = s;
    __syncthreads();
    if (threadIdx.x == 0)
        atomicAdd(&out[b], ws4[0] + ws4[1] + ws4[2] + ws4[3]);
}

extern "C" void kernel_launch(void* const* d_in, const int* in_sizes, int n_in,
                              void* d_out, int out_size, void* d_ws, size_t ws_size,
                              hipStream_t stream) {
    const float* s1 = (const float*)d_in[0];
    const float* s2 = (const float*)d_in[1];
    float* out = (float*)d_out;

    // ws: norms(BN+BM f32, pre-scaled -0.5x) | bfA | bfB | rowpart | colpart
    float* norms         = (float*)d_ws;
    unsigned short* bfA  = (unsigned short*)(norms + BN_ + BM_);
    unsigned short* bfB  = bfA + (size_t)BN_ * C_;
    float* rowpart       = (float*)(bfB + (size_t)BM_ * C_);
    float* colpart       = rowpart + (size_t)4 * B_ * N_;

    prep_kernel<<<(BN_ + BM_) / 16, 256, 0, stream>>>(
        s1, s2, norms, bfA, bfB, out);

    dim3 grid(N_ / 128, M_ / 1024, B_);
    hausdorff_mfma<<<grid, 256, 0, stream>>>(
        bfA, bfB, norms, norms + BN_, rowpart, colpart);

    hausdorff_reduce<<<B_ * 8, 256, 0, stream>>>(rowpart, colpart, out);
}